// Round 2
// baseline (229.332 us; speedup 1.0000x reference)
//
#include <hip/hip_runtime.h>

#define ALPHA 0.1f
#define NUM_CLASSES 10

// ---------------------------------------------------------------------------
// Workspace layout (floats/uints):
//   ct[64*256]   : centers transposed, ct[j*256 + k] = centers[k*64 + j]
//   c2[256]      : ||c_k||^2
//   loss_acc[1]  : float loss accumulator
//   counts[100]  : uint counts[cluster<10][label]
// ---------------------------------------------------------------------------

__global__ __launch_bounds__(256) void prep_kernel(
    const float* __restrict__ centers,
    float* __restrict__ ct,
    float* __restrict__ c2,
    float* __restrict__ loss_acc,
    unsigned int* __restrict__ counts)
{
    const int k = threadIdx.x;  // 0..255, one center per thread
    const float4* crow = (const float4*)(centers + k * 64);
    float s = 0.f;
#pragma unroll
    for (int j4 = 0; j4 < 16; ++j4) {
        float4 v = crow[j4];
        int j = j4 * 4;
        ct[(j + 0) * 256 + k] = v.x;
        ct[(j + 1) * 256 + k] = v.y;
        ct[(j + 2) * 256 + k] = v.z;
        ct[(j + 3) * 256 + k] = v.w;
        s += v.x * v.x + v.y * v.y + v.z * v.z + v.w * v.w;
    }
    c2[k] = s;
    if (k < NUM_CLASSES * NUM_CLASSES) counts[k] = 0u;
    if (k == 0) loss_acc[0] = 0.f;
}

// ---------------------------------------------------------------------------
// Main kernel: block = 64 points x 256 centers. 4 waves/block.
// lane  = point (64 points per block)
// wave  = 64-center chunk; center values are wave-uniform -> s_load (SMEM),
//         keeping the VALU pipe as the only hot pipe.
//
// amdgpu_waves_per_eu(2,4): round-1 showed VGPR_Count=40 + ~50% occupancy --
// the allocator had shuffled acc[64] into AGPRs (accvgpr_read/fma/accvgpr_write
// = 3x VALU per accumulate, matching the 150us vs 55us-floor measurement).
// Min=2 waves/EU gives a 256-reg budget so acc stays in arch VGPRs; max=4
// removes the incentive to squeeze registers for occupancy.
// ---------------------------------------------------------------------------

__global__ __launch_bounds__(256)
__attribute__((amdgpu_waves_per_eu(2, 4)))
void dist_kernel(
    const float* __restrict__ x,
    const int*   __restrict__ y,
    const float* __restrict__ ct,
    const float* __restrict__ c2,
    float* __restrict__ loss_acc,
    unsigned int* __restrict__ counts,
    int N)
{
    const int wave = __builtin_amdgcn_readfirstlane(threadIdx.x >> 6);
    const int lane = threadIdx.x & 63;
    const int m = blockIdx.x * 64 + lane;   // point index (N % 64 == 0)
    const int kbase = wave * 64;            // this wave's center chunk

    const float* __restrict__ xrow = x + (size_t)m * 64;

    float acc[64];
#pragma unroll
    for (int k = 0; k < 64; ++k) acc[k] = 0.f;
    float x2 = 0.f;

    for (int j4 = 0; j4 < 16; ++j4) {
        float4 xv = ((const float4*)xrow)[j4];
        x2 += xv.x * xv.x + xv.y * xv.y + xv.z * xv.z + xv.w * xv.w;
        const float* __restrict__ cr0 = ct + (j4 * 4 + 0) * 256 + kbase;
        const float* __restrict__ cr1 = ct + (j4 * 4 + 1) * 256 + kbase;
        const float* __restrict__ cr2 = ct + (j4 * 4 + 2) * 256 + kbase;
        const float* __restrict__ cr3 = ct + (j4 * 4 + 3) * 256 + kbase;
#pragma unroll
        for (int k = 0; k < 64; ++k) acc[k] = fmaf(xv.x, cr0[k], acc[k]);
#pragma unroll
        for (int k = 0; k < 64; ++k) acc[k] = fmaf(xv.y, cr1[k], acc[k]);
#pragma unroll
        for (int k = 0; k < 64; ++k) acc[k] = fmaf(xv.z, cr2[k], acc[k]);
#pragma unroll
        for (int k = 0; k < 64; ++k) acc[k] = fmaf(xv.w, cr3[k], acc[k]);
    }

    // Epilogue: per-lane over this wave's 64 centers.
    float swe = 0.f, swd = 0.f;
    float dmin = 3.4e38f;
    int kmin = 0;
#pragma unroll
    for (int k = 0; k < 64; ++k) {
        float d = x2 + c2[kbase + k] - 2.f * acc[k];
        d = fmaxf(d, 0.f);
        if (d < dmin) { dmin = d; kmin = k; }   // strict < : first-min in k order
        // (1+d)^(-alpha) = exp2(-alpha * log2(1+d))
        float w = exp2f(-ALPHA * __log2f(1.f + d));
        swe += w;
        swd += w * d;
    }

    // Cross-wave combine (4 waves cover 256 centers of the same 64 points).
    __shared__ float s_swe[4][64];
    __shared__ float s_swd[4][64];
    __shared__ float s_dmin[4][64];
    __shared__ int   s_kmin[4][64];
    s_swe[wave][lane] = swe;
    s_swd[wave][lane] = swd;
    s_dmin[wave][lane] = dmin;
    s_kmin[wave][lane] = kbase + kmin;
    __syncthreads();

    if (wave == 0) {
        float SWE = s_swe[0][lane];
        float SWD = s_swd[0][lane];
        float best = s_dmin[0][lane];
        int bk = s_kmin[0][lane];
#pragma unroll
        for (int w = 1; w < 4; ++w) {
            SWE += s_swe[w][lane];
            SWD += s_swd[w][lane];
            float dv = s_dmin[w][lane];
            int kv = s_kmin[w][lane];
            if (dv < best) { best = dv; bk = kv; }  // strict < keeps lowest wave on ties
        }
        float loss_n = SWD / SWE;

        if (bk < NUM_CLASSES) {
            int label = y[m];
            atomicAdd(&counts[bk * NUM_CLASSES + label], 1u);
        }

        // Reduce loss across the 64 lanes (one point each) -> one atomic/block.
#pragma unroll
        for (int off = 32; off > 0; off >>= 1)
            loss_n += __shfl_down(loss_n, off, 64);
        if (lane == 0) atomicAdd(loss_acc, loss_n);
    }
}

// ---------------------------------------------------------------------------
// Finalize: greedy cluster->label assignment, exactly mirroring the reference.
// ---------------------------------------------------------------------------

__global__ void finalize_kernel(
    const float* __restrict__ loss_acc,
    const unsigned int* __restrict__ counts,
    float* __restrict__ out,
    int N)
{
    if (threadIdx.x == 0 && blockIdx.x == 0) {
        float c[NUM_CLASSES][NUM_CLASSES];
        for (int i = 0; i < NUM_CLASSES; ++i)
            for (int j = 0; j < NUM_CLASSES; ++j)
                c[i][j] = (float)counts[i * NUM_CLASSES + j];

        bool used[NUM_CLASSES];
        for (int i = 0; i < NUM_CLASSES; ++i) used[i] = false;

        float correct = 0.f;
        for (int i = 0; i < NUM_CLASSES; ++i) {
            float rowsum = 0.f;
            for (int j = 0; j < NUM_CLASSES; ++j) rowsum += c[i][j];
            bool has_points = rowsum > 0.f;

            // first-index argmax of the raw row
            int label = 0;
            float mx = c[i][0];
            for (int j = 1; j < NUM_CLASSES; ++j)
                if (c[i][j] > mx) { mx = c[i][j]; label = j; }

            if (used[label]) {
                // first-index argmax of the used-masked row
                float mm = used[0] ? 0.f : c[i][0];
                int l2 = 0;
                for (int j = 1; j < NUM_CLASSES; ++j) {
                    float v = used[j] ? 0.f : c[i][j];
                    if (v > mm) { mm = v; l2 = j; }
                }
                label = l2;
            }

            if (has_points) {
                correct += c[i][label];
                used[label] = true;
            }
        }
        out[0] = loss_acc[0];
        out[1] = correct / (float)N;
    }
}

// ---------------------------------------------------------------------------

extern "C" void kernel_launch(void* const* d_in, const int* in_sizes, int n_in,
                              void* d_out, int out_size, void* d_ws, size_t ws_size,
                              hipStream_t stream)
{
    const float* x       = (const float*)d_in[0];
    const int*   y       = (const int*)d_in[1];
    const float* centers = (const float*)d_in[2];
    float* out = (float*)d_out;

    const int N = in_sizes[0] / 64;  // D = 64

    float* ct = (float*)d_ws;                         // 64*256 floats
    float* c2 = ct + 64 * 256;                        // 256 floats
    float* loss_acc = c2 + 256;                       // 1 float
    unsigned int* counts = (unsigned int*)(loss_acc + 1);  // 100 uints

    prep_kernel<<<1, 256, 0, stream>>>(centers, ct, c2, loss_acc, counts);
    dist_kernel<<<N / 64, 256, 0, stream>>>(x, y, ct, c2, loss_acc, counts, N);
    finalize_kernel<<<1, 64, 0, stream>>>(loss_acc, counts, out, N);
}

// Round 3
// 213.183 us; speedup vs baseline: 1.0758x; 1.0758x over previous
//
#include <hip/hip_runtime.h>

#define ALPHA 0.1f
#define NUM_CLASSES 10

typedef __attribute__((ext_vector_type(8))) short bf16x8;
typedef __attribute__((ext_vector_type(4))) float f32x4;

// ---------------------------------------------------------------------------
// ws layout (bytes):
//   ctbf  @ 0      : ushort[256*192]  B' = [ch | cl | ch] per center row (98304 B)
//   c2    @ 98304  : float[256]
//   loss  @ 99328  : float[1]
//   counts@ 99332  : uint[100]
// ---------------------------------------------------------------------------

__device__ __forceinline__ unsigned pack_hi(float a, float b) {
    // bf16(a) in low 16, bf16(b) in high 16 (truncation split -> exact Dekker hi part)
    return (__float_as_uint(b) & 0xFFFF0000u) | (__float_as_uint(a) >> 16);
}
__device__ __forceinline__ float truncbf(float a) {
    return __uint_as_float(__float_as_uint(a) & 0xFFFF0000u);
}
__device__ __forceinline__ float dppmovf(float v, int ctrl);
__device__ __forceinline__ unsigned dppmovu(unsigned v, int ctrl);

#define DPPF(v, CTRL) __int_as_float(__builtin_amdgcn_update_dpp(0, __float_as_int(v), CTRL, 0xF, 0xF, true))
#define DPPU(v, CTRL) ((unsigned)__builtin_amdgcn_update_dpp(0, (int)(v), CTRL, 0xF, 0xF, true))

// sum over the 16-lane DPP row (result in every lane): xor1, xor2, ror4, ror8
#define ROWSUM16(v) { v += DPPF(v, 0xB1); v += DPPF(v, 0x4E); v += DPPF(v, 0x124); v += DPPF(v, 0x128); }
// 64-bit (d_bits, k) min over the 16-lane row: first-index argmin semantics
#define ROWMIN_STEP(CTRL) { unsigned h2 = DPPU(bh, CTRL); unsigned l2 = DPPU(blo, CTRL); \
    bool tk = (h2 < bh) | ((h2 == bh) & (l2 < blo)); bh = tk ? h2 : bh; blo = tk ? l2 : blo; }
#define ROWMIN16() { ROWMIN_STEP(0xB1) ROWMIN_STEP(0x4E) ROWMIN_STEP(0x124) ROWMIN_STEP(0x128) }

// ---------------------------------------------------------------------------

__global__ __launch_bounds__(256) void prep_kernel(
    const float* __restrict__ centers,
    unsigned short* __restrict__ ctbf,
    float* __restrict__ c2,
    float* __restrict__ loss_acc,
    unsigned int* __restrict__ counts)
{
    const int k = threadIdx.x;  // one center per thread
    const float* crow = centers + k * 64;
    float s = 0.f;
#pragma unroll
    for (int d = 0; d < 64; ++d) {
        float c = crow[d];
        s += c * c;
        unsigned bits = __float_as_uint(c);
        unsigned short chb = (unsigned short)(bits >> 16);
        float cl = c - truncbf(c);
        unsigned short clb = (unsigned short)(__float_as_uint(cl) >> 16);
        ctbf[k * 192 + d]       = chb;   // term 1: xh*ch
        ctbf[k * 192 + 64 + d]  = clb;   // term 2: xh*cl
        ctbf[k * 192 + 128 + d] = chb;   // term 3: xl*ch
    }
    c2[k] = s;
    if (k < NUM_CLASSES * NUM_CLASSES) counts[k] = 0u;
    if (k == 0) loss_acc[0] = 0.f;
}

// ---------------------------------------------------------------------------
// dist kernel: 512 threads = 8 waves = (pg in {0,1} point-halves) x (cg in 0..3
// center-quarters). Per m-tile: 128 points x 256 centers, K'=192 bf16.
// B' resident in LDS for the whole block (padded rows: 200 ushorts = 400 B,
// 2-way bank aliasing only). x loads global->VGPR, split in-register.
// ---------------------------------------------------------------------------

__global__ __launch_bounds__(512, 2) void dist_kernel(
    const float* __restrict__ x,
    const int*   __restrict__ y,
    const unsigned short* __restrict__ ctbf,
    const float* __restrict__ c2g,
    float* __restrict__ loss_acc,
    unsigned int* __restrict__ counts,
    int NT)
{
    extern __shared__ char smem[];
    float* x2s                 = (float*)(smem + 102400);                 // [128]
    float* swe_c               = (float*)(smem + 102912);                 // [4][128]
    float* swd_c               = (float*)(smem + 104960);                 // [4][128]
    unsigned long long* best_c = (unsigned long long*)(smem + 107008);    // [4][128]

    const int tid  = threadIdx.x;
    const int w    = tid >> 6;
    const int lane = tid & 63;
    const int q    = lane >> 4;   // k-group within frag
    const int r    = lane & 15;   // m/n index within 16-tile
    const int cg   = w & 3;       // center quarter (64 centers)
    const int pg   = w >> 2;      // point half (64 points)

    // Stage B' into LDS once per block (rows padded 384B -> 400B).
    for (int i = tid; i < 6144; i += 512) {
        int row = i / 24;
        int c   = i - row * 24;
        *(uint4*)(smem + row * 400 + c * 16) =
            *(const uint4*)((const char*)ctbf + row * 384 + c * 16);
    }

    // This lane's 4 center norms (centers cg*64 + nt*16 + r).
    float c2r[4];
#pragma unroll
    for (int nt = 0; nt < 4; ++nt) c2r[nt] = c2g[cg * 64 + nt * 16 + r];

    __syncthreads();

    float loss_local = 0.f;

    for (int t = blockIdx.x; t < NT; t += gridDim.x) {
        const int mb = t * 128 + pg * 64;

        // ---- load x rows, truncation-split to bf16 frags, compute x2 ----
        bf16x8 afrag[4][4];   // [m-subtile][{xh_lo, xh_hi, xl_lo, xl_hi}]
#pragma unroll
        for (int mt = 0; mt < 4; ++mt) {
            const int row = mb + mt * 16 + r;
            const float4* X = (const float4*)(x + (size_t)row * 64);
            float4 v0 = X[q * 2], v1 = X[q * 2 + 1];
            float4 v2 = X[8 + q * 2], v3 = X[9 + q * 2];

            float p = v0.x * v0.x;
            p = fmaf(v0.y, v0.y, p); p = fmaf(v0.z, v0.z, p); p = fmaf(v0.w, v0.w, p);
            p = fmaf(v1.x, v1.x, p); p = fmaf(v1.y, v1.y, p); p = fmaf(v1.z, v1.z, p); p = fmaf(v1.w, v1.w, p);
            p = fmaf(v2.x, v2.x, p); p = fmaf(v2.y, v2.y, p); p = fmaf(v2.z, v2.z, p); p = fmaf(v2.w, v2.w, p);
            p = fmaf(v3.x, v3.x, p); p = fmaf(v3.y, v3.y, p); p = fmaf(v3.z, v3.z, p); p = fmaf(v3.w, v3.w, p);
            p += __shfl_xor(p, 16);
            p += __shfl_xor(p, 32);
            if (cg == 0 && q == 0) x2s[pg * 64 + mt * 16 + r] = p;  // read after bar1

            union { bf16x8 v; int i[4]; } h0, h1, l0, l1;
            h0.i[0] = pack_hi(v0.x, v0.y); h0.i[1] = pack_hi(v0.z, v0.w);
            h0.i[2] = pack_hi(v1.x, v1.y); h0.i[3] = pack_hi(v1.z, v1.w);
            h1.i[0] = pack_hi(v2.x, v2.y); h1.i[1] = pack_hi(v2.z, v2.w);
            h1.i[2] = pack_hi(v3.x, v3.y); h1.i[3] = pack_hi(v3.z, v3.w);
            l0.i[0] = pack_hi(v0.x - truncbf(v0.x), v0.y - truncbf(v0.y));
            l0.i[1] = pack_hi(v0.z - truncbf(v0.z), v0.w - truncbf(v0.w));
            l0.i[2] = pack_hi(v1.x - truncbf(v1.x), v1.y - truncbf(v1.y));
            l0.i[3] = pack_hi(v1.z - truncbf(v1.z), v1.w - truncbf(v1.w));
            l1.i[0] = pack_hi(v2.x - truncbf(v2.x), v2.y - truncbf(v2.y));
            l1.i[1] = pack_hi(v2.z - truncbf(v2.z), v2.w - truncbf(v2.w));
            l1.i[2] = pack_hi(v3.x - truncbf(v3.x), v3.y - truncbf(v3.y));
            l1.i[3] = pack_hi(v3.z - truncbf(v3.z), v3.w - truncbf(v3.w));
            afrag[mt][0] = h0.v; afrag[mt][1] = h1.v;
            afrag[mt][2] = l0.v; afrag[mt][3] = l1.v;
        }

        // ---- K'=192 MFMA main loop: 6 k-steps x 4x4 subtiles ----
        f32x4 acc[4][4];
#pragma unroll
        for (int mt = 0; mt < 4; ++mt)
#pragma unroll
            for (int nt = 0; nt < 4; ++nt) acc[mt][nt] = (f32x4){0.f, 0.f, 0.f, 0.f};

#pragma unroll
        for (int s = 0; s < 6; ++s) {
            const int fi = (s < 4) ? (s & 1) : 2 + (s & 1);
            bf16x8 bfrag[4];
#pragma unroll
            for (int nt = 0; nt < 4; ++nt) {
                const int n = cg * 64 + nt * 16 + r;
                bfrag[nt] = *(const bf16x8*)(smem + n * 400 + s * 64 + q * 16);
            }
#pragma unroll
            for (int mt = 0; mt < 4; ++mt)
#pragma unroll
                for (int nt = 0; nt < 4; ++nt)
                    acc[mt][nt] = __builtin_amdgcn_mfma_f32_16x16x32_bf16(
                        afrag[mt][fi], bfrag[nt], acc[mt][nt], 0, 0, 0);
        }

        __syncthreads();  // bar1: x2s written (pre-MFMA) now visible to all waves

        // ---- epilogue: C/D layout row=(q*4+reg), col=r ----
#pragma unroll
        for (int mt = 0; mt < 4; ++mt) {
#pragma unroll
            for (int reg = 0; reg < 4; ++reg) {
                const int lp = pg * 64 + mt * 16 + q * 4 + reg;  // local point
                const float x2v = x2s[lp];
                float swe = 0.f, swd = 0.f;
                unsigned bh = 0xFFFFFFFFu, blo = 0xFFFFFFFFu;
#pragma unroll
                for (int nt = 0; nt < 4; ++nt) {
                    float S = acc[mt][nt][reg];
                    float d = fmaf(-2.f, S, x2v + c2r[nt]);
                    d = fmaxf(d, 0.f);
                    float wg = exp2f(-ALPHA * __log2f(1.f + d));
                    swe += wg;
                    swd = fmaf(wg, d, swd);
                    unsigned db = __float_as_uint(d);
                    unsigned k  = (unsigned)(cg * 64 + nt * 16 + r);
                    bool tk = (db < bh) | ((db == bh) & (k < blo));
                    bh = tk ? db : bh; blo = tk ? k : blo;
                }
                ROWSUM16(swe)
                ROWSUM16(swd)
                ROWMIN16()
                if (r == 0) {
                    swe_c[cg * 128 + lp] = swe;
                    swd_c[cg * 128 + lp] = swd;
                    best_c[cg * 128 + lp] = ((unsigned long long)bh << 32) | blo;
                }
            }
        }
        __syncthreads();  // bar2: partials visible

        if (tid < 128) {
            const int lp = tid;
            float SWE = 0.f, SWD = 0.f;
            unsigned long long best = ~0ull;
#pragma unroll
            for (int g = 0; g < 4; ++g) {
                SWE += swe_c[g * 128 + lp];
                SWD += swd_c[g * 128 + lp];
                unsigned long long b = best_c[g * 128 + lp];
                best = (b < best) ? b : best;
            }
            loss_local += SWD / SWE;
            const unsigned bk = (unsigned)best;  // low 32 bits = center index
            if (bk < NUM_CLASSES) {
                const int lbl = y[t * 128 + lp];
                atomicAdd(&counts[bk * NUM_CLASSES + lbl], 1u);
            }
        }
        __syncthreads();  // bar3: protect x2s/comb for next tile
    }

    // final loss reduction (only waves 0,1 hold nonzero loss_local)
    if (w < 2) {
        float v = loss_local;
#pragma unroll
        for (int o = 32; o > 0; o >>= 1) v += __shfl_down(v, o);
        if (lane == 0) atomicAdd(loss_acc, v);
    }
}

// ---------------------------------------------------------------------------
// Finalize: greedy cluster->label assignment, exactly mirroring the reference.
// ---------------------------------------------------------------------------

__global__ void finalize_kernel(
    const float* __restrict__ loss_acc,
    const unsigned int* __restrict__ counts,
    float* __restrict__ out,
    int N)
{
    if (threadIdx.x == 0 && blockIdx.x == 0) {
        float c[NUM_CLASSES][NUM_CLASSES];
        for (int i = 0; i < NUM_CLASSES; ++i)
            for (int j = 0; j < NUM_CLASSES; ++j)
                c[i][j] = (float)counts[i * NUM_CLASSES + j];

        bool used[NUM_CLASSES];
        for (int i = 0; i < NUM_CLASSES; ++i) used[i] = false;

        float correct = 0.f;
        for (int i = 0; i < NUM_CLASSES; ++i) {
            float rowsum = 0.f;
            for (int j = 0; j < NUM_CLASSES; ++j) rowsum += c[i][j];
            bool has_points = rowsum > 0.f;

            int label = 0;
            float mx = c[i][0];
            for (int j = 1; j < NUM_CLASSES; ++j)
                if (c[i][j] > mx) { mx = c[i][j]; label = j; }

            if (used[label]) {
                float mm = used[0] ? 0.f : c[i][0];
                int l2 = 0;
                for (int j = 1; j < NUM_CLASSES; ++j) {
                    float v = used[j] ? 0.f : c[i][j];
                    if (v > mm) { mm = v; l2 = j; }
                }
                label = l2;
            }

            if (has_points) {
                correct += c[i][label];
                used[label] = true;
            }
        }
        out[0] = loss_acc[0];
        out[1] = correct / (float)N;
    }
}

// ---------------------------------------------------------------------------

extern "C" void kernel_launch(void* const* d_in, const int* in_sizes, int n_in,
                              void* d_out, int out_size, void* d_ws, size_t ws_size,
                              hipStream_t stream)
{
    const float* x       = (const float*)d_in[0];
    const int*   y       = (const int*)d_in[1];
    const float* centers = (const float*)d_in[2];
    float* out = (float*)d_out;

    const int N  = in_sizes[0] / 64;  // D = 64
    const int NT = N / 128;           // 128-point m-tiles

    unsigned short* ctbf = (unsigned short*)d_ws;              // 98304 B
    float* c2      = (float*)((char*)d_ws + 98304);            // 1024 B
    float* loss    = (float*)((char*)d_ws + 99328);            // 4 B
    unsigned int* counts = (unsigned int*)((char*)d_ws + 99332);  // 400 B

    static const size_t SMEM = 111104;
    static int once = [] {
        hipFuncSetAttribute((const void*)dist_kernel,
                            hipFuncAttributeMaxDynamicSharedMemorySize, (int)SMEM);
        return 0;
    }();
    (void)once;

    prep_kernel<<<1, 256, 0, stream>>>(centers, ctbf, c2, loss, counts);

    int grid = 256;
    if (grid > NT) grid = NT;
    dist_kernel<<<grid, 512, SMEM, stream>>>(x, y, ctbf, c2, loss, counts, NT);

    finalize_kernel<<<1, 64, 0, stream>>>(loss, counts, out, N);
}

// Round 4
// 160.956 us; speedup vs baseline: 1.4248x; 1.3245x over previous
//
#include <hip/hip_runtime.h>

#define ALPHA 0.1f
#define NUM_CLASSES 10

typedef __attribute__((ext_vector_type(8))) short bf16x8;
typedef __attribute__((ext_vector_type(4))) float f32x4;

// ---------------------------------------------------------------------------
// ws layout (bytes):
//   ctpk  @ 0     : ushort[4cg][4ct][4f][64lane][8] pre-packed center A-frags
//                   f: 0=ch k0..31, 1=ch k32..63, 2=cl k0..31, 3=cl k32..63
//                   (65536 B)
//   c2    @ 65536 : float[256]
//   loss  @ 66560 : float[1]
//   counts@ 66564 : uint[100]
// ---------------------------------------------------------------------------

__device__ __forceinline__ unsigned pack2(float a, float b) {
    // bf16(a) lo16 | bf16(b) hi16 (truncation -> exact Dekker hi part)
    return (__float_as_uint(b) & 0xFFFF0000u) | (__float_as_uint(a) >> 16);
}
__device__ __forceinline__ float truncbf(float a) {
    return __uint_as_float(__float_as_uint(a) & 0xFFFF0000u);
}

// ---------------------------------------------------------------------------

__global__ __launch_bounds__(256) void prep_kernel(
    const float* __restrict__ centers,
    unsigned int* __restrict__ ctpk,   // viewed as uint4-able uints
    float* __restrict__ c2,
    float* __restrict__ loss_acc,
    unsigned int* __restrict__ counts)
{
    const int k = threadIdx.x;          // center id 0..255
    const int cg = k >> 6, ct = (k >> 4) & 3, r = k & 15;

    float cv[64];
    float s = 0.f;
    const float4* crow = (const float4*)(centers + k * 64);
#pragma unroll
    for (int j4 = 0; j4 < 16; ++j4) {
        float4 v = crow[j4];
        cv[j4 * 4 + 0] = v.x; cv[j4 * 4 + 1] = v.y;
        cv[j4 * 4 + 2] = v.z; cv[j4 * 4 + 3] = v.w;
        s += v.x * v.x + v.y * v.y + v.z * v.z + v.w * v.w;
    }
    c2[k] = s;

    uint4* out4 = (uint4*)ctpk;
#pragma unroll
    for (int f = 0; f < 4; ++f) {
#pragma unroll
        for (int q = 0; q < 4; ++q) {
            const int cbase = (f & 1) * 32 + q * 8;   // source col of j=0
            unsigned wv[4];
#pragma unroll
            for (int j2 = 0; j2 < 4; ++j2) {
                float a = cv[cbase + j2 * 2], b = cv[cbase + j2 * 2 + 1];
                if (f >= 2) { a = a - truncbf(a); b = b - truncbf(b); }  // cl part
                wv[j2] = pack2(a, b);
            }
            const int lane = q * 16 + r;
            out4[((cg * 4 + ct) * 4 + f) * 64 + lane] =
                make_uint4(wv[0], wv[1], wv[2], wv[3]);
        }
    }
    if (k < NUM_CLASSES * NUM_CLASSES) counts[k] = 0u;
    if (k == 0) loss_acc[0] = 0.f;
}

// ---------------------------------------------------------------------------
// dist kernel: block = 256 threads = 4 waves; wave cg handles centers
// [cg*64, cg*64+64) x the tile's 64 points. Centers = M dim of the MFMA,
// points = N dim: C/D row = center (q*4+reg), col = point (r), so each lane
// accumulates 16 in-lane center values per point -> cheap epilogue.
// Center A-frags are tile-invariant: loaded once into 64 VGPRs. No LDS in
// the K loop; 3 KB LDS only for the cross-wave (4 center-quarter) combine.
// ---------------------------------------------------------------------------

__global__ __launch_bounds__(256, 2) void dist_kernel(
    const float* __restrict__ x,
    const int*   __restrict__ y,
    const unsigned int* __restrict__ ctpk,
    const float* __restrict__ c2g,
    float* __restrict__ loss_acc,
    unsigned int* __restrict__ counts,
    int NT)
{
    __shared__ float    comb_swe[4][64];
    __shared__ float    comb_swd[4][64];
    __shared__ unsigned comb_best[4][64];

    const int tid  = threadIdx.x;
    const int cg   = tid >> 6;     // wave = center quarter
    const int lane = tid & 63;
    const int q    = lane >> 4;
    const int r    = lane & 15;

    // ---- tile-invariant: center A-frags (64 VGPRs) + this lane's c2 (16) ----
    bf16x8 af[4][4];   // [ct][f]
    const uint4* cp4 = (const uint4*)ctpk;
#pragma unroll
    for (int ct = 0; ct < 4; ++ct)
#pragma unroll
        for (int f = 0; f < 4; ++f) {
            union { uint4 u; bf16x8 v; } tmp;
            tmp.u = cp4[((cg * 4 + ct) * 4 + f) * 64 + lane];
            af[ct][f] = tmp.v;
        }

    float c2r[4][4];
#pragma unroll
    for (int ct = 0; ct < 4; ++ct) {
        float4 v = *(const float4*)(c2g + cg * 64 + ct * 16 + q * 4);
        c2r[ct][0] = v.x; c2r[ct][1] = v.y; c2r[ct][2] = v.z; c2r[ct][3] = v.w;
    }

    float loss_local = 0.f;

    for (int t = blockIdx.x; t < NT; t += gridDim.x) {
        // ---- load + split x for the tile's 64 points (B-operand frags) ----
        bf16x8 bh0[4], bh1[4], bl0[4], bl1[4];
        float x2v[4];
#pragma unroll
        for (int pt = 0; pt < 4; ++pt) {
            const int row = t * 64 + pt * 16 + r;
            const float4* X = (const float4*)(x + (size_t)row * 64);
            float4 v0 = X[q * 2], v1 = X[q * 2 + 1];        // cols q*8 .. q*8+7
            float4 v2 = X[8 + q * 2], v3 = X[9 + q * 2];    // cols 32+q*8 ..

            float p = v0.x * v0.x;
            p = fmaf(v0.y, v0.y, p); p = fmaf(v0.z, v0.z, p); p = fmaf(v0.w, v0.w, p);
            p = fmaf(v1.x, v1.x, p); p = fmaf(v1.y, v1.y, p); p = fmaf(v1.z, v1.z, p); p = fmaf(v1.w, v1.w, p);
            p = fmaf(v2.x, v2.x, p); p = fmaf(v2.y, v2.y, p); p = fmaf(v2.z, v2.z, p); p = fmaf(v2.w, v2.w, p);
            p = fmaf(v3.x, v3.x, p); p = fmaf(v3.y, v3.y, p); p = fmaf(v3.z, v3.z, p); p = fmaf(v3.w, v3.w, p);
            p += __shfl_xor(p, 16);
            p += __shfl_xor(p, 32);
            x2v[pt] = p;

            union { bf16x8 v; unsigned u[4]; } h0, h1, l0, l1;
            h0.u[0] = pack2(v0.x, v0.y); h0.u[1] = pack2(v0.z, v0.w);
            h0.u[2] = pack2(v1.x, v1.y); h0.u[3] = pack2(v1.z, v1.w);
            h1.u[0] = pack2(v2.x, v2.y); h1.u[1] = pack2(v2.z, v2.w);
            h1.u[2] = pack2(v3.x, v3.y); h1.u[3] = pack2(v3.z, v3.w);
            l0.u[0] = pack2(v0.x - truncbf(v0.x), v0.y - truncbf(v0.y));
            l0.u[1] = pack2(v0.z - truncbf(v0.z), v0.w - truncbf(v0.w));
            l0.u[2] = pack2(v1.x - truncbf(v1.x), v1.y - truncbf(v1.y));
            l0.u[3] = pack2(v1.z - truncbf(v1.z), v1.w - truncbf(v1.w));
            l1.u[0] = pack2(v2.x - truncbf(v2.x), v2.y - truncbf(v2.y));
            l1.u[1] = pack2(v2.z - truncbf(v2.z), v2.w - truncbf(v2.w));
            l1.u[2] = pack2(v3.x - truncbf(v3.x), v3.y - truncbf(v3.y));
            l1.u[3] = pack2(v3.z - truncbf(v3.z), v3.w - truncbf(v3.w));
            bh0[pt] = h0.v; bh1[pt] = h1.v; bl0[pt] = l0.v; bl1[pt] = l1.v;
        }

        // ---- MFMA: S = C' . X'^T, 3-term split, 96 MFMAs ----
        f32x4 acc[4][4];   // [ct][pt]
#pragma unroll
        for (int ct = 0; ct < 4; ++ct)
#pragma unroll
            for (int pt = 0; pt < 4; ++pt) acc[ct][pt] = (f32x4){0.f, 0.f, 0.f, 0.f};

#pragma unroll
        for (int ct = 0; ct < 4; ++ct)
#pragma unroll
            for (int pt = 0; pt < 4; ++pt) {
                f32x4 a = acc[ct][pt];
                a = __builtin_amdgcn_mfma_f32_16x16x32_bf16(af[ct][0], bh0[pt], a, 0, 0, 0); // ch.xh k0-31
                a = __builtin_amdgcn_mfma_f32_16x16x32_bf16(af[ct][1], bh1[pt], a, 0, 0, 0); // ch.xh k32-63
                a = __builtin_amdgcn_mfma_f32_16x16x32_bf16(af[ct][2], bh0[pt], a, 0, 0, 0); // cl.xh
                a = __builtin_amdgcn_mfma_f32_16x16x32_bf16(af[ct][3], bh1[pt], a, 0, 0, 0);
                a = __builtin_amdgcn_mfma_f32_16x16x32_bf16(af[ct][0], bl0[pt], a, 0, 0, 0); // ch.xl
                a = __builtin_amdgcn_mfma_f32_16x16x32_bf16(af[ct][1], bl1[pt], a, 0, 0, 0);
                acc[ct][pt] = a;
            }

        // ---- epilogue: lane holds 16 centers (ct x reg) per point ----
#pragma unroll
        for (int pt = 0; pt < 4; ++pt) {
            float swe = 0.f, swd = 0.f;
            unsigned best = 0xFFFFFFFFu;
            const float x2p = x2v[pt];
#pragma unroll
            for (int ct = 0; ct < 4; ++ct) {
#pragma unroll
                for (int reg = 0; reg < 4; ++reg) {
                    float d = fmaf(-2.f, acc[ct][pt][reg], x2p + c2r[ct][reg]);
                    d = fmaxf(d, 0.f);
                    const unsigned kid = (unsigned)(cg * 64 + ct * 16 + q * 4 + reg);
                    unsigned u = (__float_as_uint(d) & 0xFFFFFF00u) | kid;
                    best = min(best, u);
                    float wg = exp2f(-ALPHA * __log2f(1.f + d));
                    swe += wg;
                    swd = fmaf(wg, d, swd);
                }
            }
            // reduce over q (4 lanes share point pt*16+r)
            swe += __shfl_xor(swe, 16); swe += __shfl_xor(swe, 32);
            swd += __shfl_xor(swd, 16); swd += __shfl_xor(swd, 32);
            best = min(best, (unsigned)__shfl_xor((int)best, 16));
            best = min(best, (unsigned)__shfl_xor((int)best, 32));
            if (q == 0) {
                comb_swe[cg][pt * 16 + r] = swe;
                comb_swd[cg][pt * 16 + r] = swd;
                comb_best[cg][pt * 16 + r] = best;
            }
        }
        __syncthreads();

        if (tid < 64) {
            float SWE = comb_swe[0][tid], SWD = comb_swd[0][tid];
            unsigned BEST = comb_best[0][tid];
#pragma unroll
            for (int g = 1; g < 4; ++g) {
                SWE += comb_swe[g][tid];
                SWD += comb_swd[g][tid];
                BEST = min(BEST, comb_best[g][tid]);
            }
            loss_local += SWD / SWE;
            const unsigned bk = BEST & 0xFFu;
            if (bk < NUM_CLASSES) {
                const int lbl = y[t * 64 + tid];
                atomicAdd(&counts[bk * NUM_CLASSES + lbl], 1u);
            }
        }
        __syncthreads();
    }

    // loss: only wave 0 (tid<64) holds nonzero loss_local
    if (cg == 0) {
        float v = loss_local;
#pragma unroll
        for (int o = 32; o > 0; o >>= 1) v += __shfl_down(v, o);
        if (lane == 0) atomicAdd(loss_acc, v);
    }
}

// ---------------------------------------------------------------------------
// Finalize: greedy cluster->label assignment, exactly mirroring the reference.
// ---------------------------------------------------------------------------

__global__ void finalize_kernel(
    const float* __restrict__ loss_acc,
    const unsigned int* __restrict__ counts,
    float* __restrict__ out,
    int N)
{
    if (threadIdx.x == 0 && blockIdx.x == 0) {
        float c[NUM_CLASSES][NUM_CLASSES];
        for (int i = 0; i < NUM_CLASSES; ++i)
            for (int j = 0; j < NUM_CLASSES; ++j)
                c[i][j] = (float)counts[i * NUM_CLASSES + j];

        bool used[NUM_CLASSES];
        for (int i = 0; i < NUM_CLASSES; ++i) used[i] = false;

        float correct = 0.f;
        for (int i = 0; i < NUM_CLASSES; ++i) {
            float rowsum = 0.f;
            for (int j = 0; j < NUM_CLASSES; ++j) rowsum += c[i][j];
            bool has_points = rowsum > 0.f;

            int label = 0;
            float mx = c[i][0];
            for (int j = 1; j < NUM_CLASSES; ++j)
                if (c[i][j] > mx) { mx = c[i][j]; label = j; }

            if (used[label]) {
                float mm = used[0] ? 0.f : c[i][0];
                int l2 = 0;
                for (int j = 1; j < NUM_CLASSES; ++j) {
                    float v = used[j] ? 0.f : c[i][j];
                    if (v > mm) { mm = v; l2 = j; }
                }
                label = l2;
            }

            if (has_points) {
                correct += c[i][label];
                used[label] = true;
            }
        }
        out[0] = loss_acc[0];
        out[1] = correct / (float)N;
    }
}

// ---------------------------------------------------------------------------

extern "C" void kernel_launch(void* const* d_in, const int* in_sizes, int n_in,
                              void* d_out, int out_size, void* d_ws, size_t ws_size,
                              hipStream_t stream)
{
    const float* x       = (const float*)d_in[0];
    const int*   y       = (const int*)d_in[1];
    const float* centers = (const float*)d_in[2];
    float* out = (float*)d_out;

    const int N  = in_sizes[0] / 64;  // D = 64
    const int NT = N / 64;            // 64-point tiles

    unsigned int* ctpk   = (unsigned int*)d_ws;                    // 65536 B
    float* c2            = (float*)((char*)d_ws + 65536);          // 1024 B
    float* loss          = (float*)((char*)d_ws + 66560);          // 4 B
    unsigned int* counts = (unsigned int*)((char*)d_ws + 66564);   // 400 B

    prep_kernel<<<1, 256, 0, stream>>>(centers, ctpk, c2, loss, counts);

    int grid = 512;                    // 2 blocks/CU (VGPR-limited), persistent
    if (grid > NT) grid = NT;
    dist_kernel<<<grid, 256, 0, stream>>>(x, y, ctpk, c2, loss, counts, NT);

    finalize_kernel<<<1, 64, 0, stream>>>(loss, counts, out, N);
}

// Round 5
// 153.299 us; speedup vs baseline: 1.4960x; 1.0499x over previous
//
#include <hip/hip_runtime.h>

#define ALPHA 0.1f
#define NUM_CLASSES 10

typedef __attribute__((ext_vector_type(8))) short bf16x8;
typedef __attribute__((ext_vector_type(4))) float f32x4;

// ---------------------------------------------------------------------------
// ws layout (bytes):
//   loss  @ 0   : float[1]
//   counts@ 4   : uint[100]
// (zeroed each launch via hipMemsetAsync; centers are packed per-block)
// ---------------------------------------------------------------------------

__device__ __forceinline__ unsigned pack2(float a, float b) {
    // bf16(a) lo16 | bf16(b) hi16 (truncation -> exact Dekker hi split)
    return (__float_as_uint(b) & 0xFFFF0000u) | (__float_as_uint(a) >> 16);
}
__device__ __forceinline__ float truncbf(float a) {
    return __uint_as_float(__float_as_uint(a) & 0xFFFF0000u);
}

// ---------------------------------------------------------------------------
// dist kernel: 512 threads = 8 waves. Wave w owns centers [w*32, w*32+32)
// (M dim of MFMA); the block processes 64-point tiles (N dim).
// Per-subtile acc reuse keeps live regs ~100 -> 2 blocks/CU = 16 waves/CU.
// Waves 0-3 convert one 16-point subtile each to bf16 split frags in LDS;
// all 8 waves read them back (conversion cost /4 vs round 4).
// ---------------------------------------------------------------------------

__global__ __launch_bounds__(512, 4) void dist_kernel(
    const float* __restrict__ x,
    const int*   __restrict__ y,
    const float* __restrict__ centers,
    float* __restrict__ loss_acc,
    unsigned int* __restrict__ counts,
    int NT)
{
    // bstage[pt][f][lane] : 16 B per lane, contiguous-lane layout (b128-friendly)
    __shared__ __align__(16) char bstage[4 * 4 * 64 * 16];   // 16 KB
    __shared__ float x2s[64];
    __shared__ float c2s[256];
    __shared__ float    comb_swe[8][64];
    __shared__ float    comb_swd[8][64];
    __shared__ unsigned comb_best[8][64];

    const int tid  = threadIdx.x;
    const int w    = tid >> 6;     // wave id = center group (32 centers)
    const int lane = tid & 63;
    const int q    = lane >> 4;
    const int r    = lane & 15;

    // ---- startup: center norms (one center per thread) ----
    if (tid < 256) {
        const float4* crow = (const float4*)(centers + tid * 64);
        float s = 0.f;
#pragma unroll
        for (int j = 0; j < 16; ++j) {
            float4 v = crow[j];
            s = fmaf(v.x, v.x, s); s = fmaf(v.y, v.y, s);
            s = fmaf(v.z, v.z, s); s = fmaf(v.w, v.w, s);
        }
        c2s[tid] = s;
    }

    // ---- startup: this wave's center A-frags (packed in-register) ----
    // af[ct][f]; f: 0=ch k0-31, 1=ch k32-63, 2=cl k0-31, 3=cl k32-63
    bf16x8 af[2][4];
#pragma unroll
    for (int ct = 0; ct < 2; ++ct) {
        const int row = w * 32 + ct * 16 + r;
        const float4* C = (const float4*)(centers + (size_t)row * 64);
        float4 v0 = C[q * 2], v1 = C[q * 2 + 1];       // k = q*8 .. q*8+7
        float4 v2 = C[8 + q * 2], v3 = C[9 + q * 2];   // k = 32+q*8 ..
        union { bf16x8 v; unsigned u[4]; } h0, h1, l0, l1;
        h0.u[0] = pack2(v0.x, v0.y); h0.u[1] = pack2(v0.z, v0.w);
        h0.u[2] = pack2(v1.x, v1.y); h0.u[3] = pack2(v1.z, v1.w);
        h1.u[0] = pack2(v2.x, v2.y); h1.u[1] = pack2(v2.z, v2.w);
        h1.u[2] = pack2(v3.x, v3.y); h1.u[3] = pack2(v3.z, v3.w);
        l0.u[0] = pack2(v0.x - truncbf(v0.x), v0.y - truncbf(v0.y));
        l0.u[1] = pack2(v0.z - truncbf(v0.z), v0.w - truncbf(v0.w));
        l0.u[2] = pack2(v1.x - truncbf(v1.x), v1.y - truncbf(v1.y));
        l0.u[3] = pack2(v1.z - truncbf(v1.z), v1.w - truncbf(v1.w));
        l1.u[0] = pack2(v2.x - truncbf(v2.x), v2.y - truncbf(v2.y));
        l1.u[1] = pack2(v2.z - truncbf(v2.z), v2.w - truncbf(v2.w));
        l1.u[2] = pack2(v3.x - truncbf(v3.x), v3.y - truncbf(v3.y));
        l1.u[3] = pack2(v3.z - truncbf(v3.z), v3.w - truncbf(v3.w));
        af[ct][0] = h0.v; af[ct][1] = h1.v; af[ct][2] = l0.v; af[ct][3] = l1.v;
    }
    __syncthreads();

    // this lane's 8 center norms: centers w*32 + ct*16 + q*4 + reg
    float c2r[2][4];
#pragma unroll
    for (int ct = 0; ct < 2; ++ct) {
        float4 v = *(const float4*)(c2s + w * 32 + ct * 16 + q * 4);
        c2r[ct][0] = v.x; c2r[ct][1] = v.y; c2r[ct][2] = v.z; c2r[ct][3] = v.w;
    }

    float loss_local = 0.f;

    for (int t = blockIdx.x; t < NT; t += gridDim.x) {
        // ---- stage: waves 0-3 convert subtile pt=w (16 points) ----
        if (w < 4) {
            const int row = t * 64 + w * 16 + r;
            const float4* X = (const float4*)(x + (size_t)row * 64);
            float4 v0 = X[q * 2], v1 = X[q * 2 + 1];
            float4 v2 = X[8 + q * 2], v3 = X[9 + q * 2];

            float p = v0.x * v0.x;
            p = fmaf(v0.y, v0.y, p); p = fmaf(v0.z, v0.z, p); p = fmaf(v0.w, v0.w, p);
            p = fmaf(v1.x, v1.x, p); p = fmaf(v1.y, v1.y, p); p = fmaf(v1.z, v1.z, p); p = fmaf(v1.w, v1.w, p);
            p = fmaf(v2.x, v2.x, p); p = fmaf(v2.y, v2.y, p); p = fmaf(v2.z, v2.z, p); p = fmaf(v2.w, v2.w, p);
            p = fmaf(v3.x, v3.x, p); p = fmaf(v3.y, v3.y, p); p = fmaf(v3.z, v3.z, p); p = fmaf(v3.w, v3.w, p);
            p += __shfl_xor(p, 16);
            p += __shfl_xor(p, 32);
            if (q == 0) x2s[w * 16 + r] = p;

            union { bf16x8 v; uint4 u4; unsigned u[4]; } h0, h1, l0, l1;
            h0.u[0] = pack2(v0.x, v0.y); h0.u[1] = pack2(v0.z, v0.w);
            h0.u[2] = pack2(v1.x, v1.y); h0.u[3] = pack2(v1.z, v1.w);
            h1.u[0] = pack2(v2.x, v2.y); h1.u[1] = pack2(v2.z, v2.w);
            h1.u[2] = pack2(v3.x, v3.y); h1.u[3] = pack2(v3.z, v3.w);
            l0.u[0] = pack2(v0.x - truncbf(v0.x), v0.y - truncbf(v0.y));
            l0.u[1] = pack2(v0.z - truncbf(v0.z), v0.w - truncbf(v0.w));
            l0.u[2] = pack2(v1.x - truncbf(v1.x), v1.y - truncbf(v1.y));
            l0.u[3] = pack2(v1.z - truncbf(v1.z), v1.w - truncbf(v1.w));
            l1.u[0] = pack2(v2.x - truncbf(v2.x), v2.y - truncbf(v2.y));
            l1.u[1] = pack2(v2.z - truncbf(v2.z), v2.w - truncbf(v2.w));
            l1.u[2] = pack2(v3.x - truncbf(v3.x), v3.y - truncbf(v3.y));
            l1.u[3] = pack2(v3.z - truncbf(v3.z), v3.w - truncbf(v3.w));
            *(uint4*)(bstage + (((w * 4 + 0) * 64 + lane) << 4)) = h0.u4;
            *(uint4*)(bstage + (((w * 4 + 1) * 64 + lane) << 4)) = h1.u4;
            *(uint4*)(bstage + (((w * 4 + 2) * 64 + lane) << 4)) = l0.u4;
            *(uint4*)(bstage + (((w * 4 + 3) * 64 + lane) << 4)) = l1.u4;
        }
        __syncthreads();   // barA: frags + x2s visible (also protects comb_* reuse)

        // ---- per 16-point subtile: MFMA then immediate epilogue (acc reuse) ----
#pragma unroll
        for (int pt = 0; pt < 4; ++pt) {
            union { uint4 u4; bf16x8 v; } b0, b1, b2, b3;
            b0.u4 = *(const uint4*)(bstage + (((pt * 4 + 0) * 64 + lane) << 4));
            b1.u4 = *(const uint4*)(bstage + (((pt * 4 + 1) * 64 + lane) << 4));
            b2.u4 = *(const uint4*)(bstage + (((pt * 4 + 2) * 64 + lane) << 4));
            b3.u4 = *(const uint4*)(bstage + (((pt * 4 + 3) * 64 + lane) << 4));
            const float x2p = x2s[pt * 16 + r];

            f32x4 acc[2];
#pragma unroll
            for (int ct = 0; ct < 2; ++ct) {
                f32x4 a = (f32x4){0.f, 0.f, 0.f, 0.f};
                a = __builtin_amdgcn_mfma_f32_16x16x32_bf16(af[ct][0], b0.v, a, 0, 0, 0); // ch.xh
                a = __builtin_amdgcn_mfma_f32_16x16x32_bf16(af[ct][1], b1.v, a, 0, 0, 0);
                a = __builtin_amdgcn_mfma_f32_16x16x32_bf16(af[ct][2], b0.v, a, 0, 0, 0); // cl.xh
                a = __builtin_amdgcn_mfma_f32_16x16x32_bf16(af[ct][3], b1.v, a, 0, 0, 0);
                a = __builtin_amdgcn_mfma_f32_16x16x32_bf16(af[ct][0], b2.v, a, 0, 0, 0); // ch.xl
                a = __builtin_amdgcn_mfma_f32_16x16x32_bf16(af[ct][1], b3.v, a, 0, 0, 0);
                acc[ct] = a;
            }

            float swe = 0.f, swd = 0.f;
            unsigned best = 0xFFFFFFFFu;
#pragma unroll
            for (int ct = 0; ct < 2; ++ct) {
#pragma unroll
                for (int reg = 0; reg < 4; ++reg) {
                    float d = fmaf(-2.f, acc[ct][reg], x2p + c2r[ct][reg]);
                    d = fmaxf(d, 0.f);
                    const unsigned kid = (unsigned)(w * 32 + ct * 16 + q * 4 + reg);
                    unsigned u = (__float_as_uint(d) & 0xFFFFFF00u) | kid;
                    best = min(best, u);
                    float wg = exp2f(-ALPHA * __log2f(1.f + d));
                    swe += wg;
                    swd = fmaf(wg, d, swd);
                }
            }
            // reduce over q (4 lanes share point pt*16+r)
            swe += __shfl_xor(swe, 16); swe += __shfl_xor(swe, 32);
            swd += __shfl_xor(swd, 16); swd += __shfl_xor(swd, 32);
            best = min(best, (unsigned)__shfl_xor((int)best, 16));
            best = min(best, (unsigned)__shfl_xor((int)best, 32));
            if (q == 0) {
                comb_swe[w][pt * 16 + r] = swe;
                comb_swd[w][pt * 16 + r] = swd;
                comb_best[w][pt * 16 + r] = best;
            }
        }
        __syncthreads();   // barB: partials visible

        // ---- combine across 8 center groups (wave 0 only) ----
        if (tid < 64) {
            float SWE = comb_swe[0][tid], SWD = comb_swd[0][tid];
            unsigned BEST = comb_best[0][tid];
#pragma unroll
            for (int g = 1; g < 8; ++g) {
                SWE += comb_swe[g][tid];
                SWD += comb_swd[g][tid];
                BEST = min(BEST, comb_best[g][tid]);
            }
            loss_local += SWD / SWE;
            const unsigned bk = BEST & 0xFFu;
            if (bk < NUM_CLASSES) {
                const int lbl = y[t * 64 + tid];
                atomicAdd(&counts[bk * NUM_CLASSES + lbl], 1u);
            }
        }
        // next iteration's barA protects comb_* / bstage / x2s
    }

    if (w == 0) {
        float v = loss_local;
#pragma unroll
        for (int o = 32; o > 0; o >>= 1) v += __shfl_down(v, o);
        if (lane == 0) atomicAdd(loss_acc, v);
    }
}

// ---------------------------------------------------------------------------
// Finalize: greedy cluster->label assignment, exactly mirroring the reference.
// ---------------------------------------------------------------------------

__global__ void finalize_kernel(
    const float* __restrict__ loss_acc,
    const unsigned int* __restrict__ counts,
    float* __restrict__ out,
    int N)
{
    if (threadIdx.x == 0 && blockIdx.x == 0) {
        float c[NUM_CLASSES][NUM_CLASSES];
        for (int i = 0; i < NUM_CLASSES; ++i)
            for (int j = 0; j < NUM_CLASSES; ++j)
                c[i][j] = (float)counts[i * NUM_CLASSES + j];

        bool used[NUM_CLASSES];
        for (int i = 0; i < NUM_CLASSES; ++i) used[i] = false;

        float correct = 0.f;
        for (int i = 0; i < NUM_CLASSES; ++i) {
            float rowsum = 0.f;
            for (int j = 0; j < NUM_CLASSES; ++j) rowsum += c[i][j];
            bool has_points = rowsum > 0.f;

            int label = 0;
            float mx = c[i][0];
            for (int j = 1; j < NUM_CLASSES; ++j)
                if (c[i][j] > mx) { mx = c[i][j]; label = j; }

            if (used[label]) {
                float mm = used[0] ? 0.f : c[i][0];
                int l2 = 0;
                for (int j = 1; j < NUM_CLASSES; ++j) {
                    float v = used[j] ? 0.f : c[i][j];
                    if (v > mm) { mm = v; l2 = j; }
                }
                label = l2;
            }

            if (has_points) {
                correct += c[i][label];
                used[label] = true;
            }
        }
        out[0] = loss_acc[0];
        out[1] = correct / (float)N;
    }
}

// ---------------------------------------------------------------------------

extern "C" void kernel_launch(void* const* d_in, const int* in_sizes, int n_in,
                              void* d_out, int out_size, void* d_ws, size_t ws_size,
                              hipStream_t stream)
{
    const float* x       = (const float*)d_in[0];
    const int*   y       = (const int*)d_in[1];
    const float* centers = (const float*)d_in[2];
    float* out = (float*)d_out;

    const int N  = in_sizes[0] / 64;  // D = 64
    const int NT = N / 64;            // 64-point tiles

    float* loss          = (float*)d_ws;                       // 4 B
    unsigned int* counts = (unsigned int*)((char*)d_ws + 4);   // 400 B

    hipMemsetAsync(d_ws, 0, 512, stream);

    int grid = 512;                    // 2 blocks/CU, persistent
    if (grid > NT) grid = NT;
    dist_kernel<<<grid, 512, 0, stream>>>(x, y, centers, loss, counts, NT);

    finalize_kernel<<<1, 64, 0, stream>>>(loss, counts, out, N);
}